// Round 12
// baseline (333.082 us; speedup 1.0000x reference)
//
#include <hip/hip_runtime.h>

// SpatialEncoding: out[src,dst] = b[min(path_len,5)-1], last-write-wins in p order.
//
// R12: TWO kernels. The scan and repack passes of R11 are DELETED — merge
// gathers directly from block-local sorted record regions (R10), with R10's
// two measured failure modes fixed:
//   (a) 272MB read-amp -> merge block covers 2 consecutive buckets with two
//       sequential LDS-tab passes; the 2 sub-spans per region are ADJACENT
//       (records sorted by bucket), so combined footprint ~45B/region -> ~125MB.
//   (b) uncoalesced starts reads -> sort dumps the starts table TRANSPOSED
//       (startsT[c][r], u16; 2.9MB footprint, L2 write-combined), so merge
//       table reads are coalesced across threads.
//
//   rec(u32) = off(14 [31:18]) | (local_p+1)(15 [17:3]) | clamped(3 [2:0])
//   merge key = ((region+1)<<18) | (rec & 0x3FFFF) — monotone in global pair
//   order (region, lp); 0 == empty. numpy last-write-wins ✓
//   startsT row c (c=0..2198): run starts of bucket c per region; row 2198 =
//   per-region totals (buckets 2198/2199 count 0 => scan sentinel).
//   NPACK=1100 keeps all packed-u16 owner accesses in-bounds (R7 lesson).
//   Zero global atomics (R1/R2/R6), no NT stores (R5), no memsets.

#define BSHIFT 14
#define BCELLS (1 << BSHIFT)            // 16384 cells per bucket
#define NBUCK  2198                     // ceil(36e6 / 16384)
#define NPACK  1100                     // 2200 u16 (pad pair keeps owners in-bounds)
#define NOWN   550                      // owner threads, 4 buckets each
#define THREADS 1024
#define TILE   12288                    // pairs per sort block
#define TROW   656                      // startsT row stride in u16 (>= nblk)
#define MGROUP 2                        // buckets per merge block

__device__ __forceinline__ unsigned int unpack16(const unsigned int* A, unsigned int c) {
    return (A[c >> 1] >> ((c & 1) * 16)) & 0xFFFFu;
}

// ---------------- K1: tile bucket-sort -> block-local sorted records ----------------
__global__ __launch_bounds__(THREADS) void se_sort(
        const int* __restrict__ src_idx,
        const int* __restrict__ dst_idx,
        const int* __restrict__ path_len,
        unsigned int* __restrict__ recsW,        // ws: [nblk][TILE] u32
        unsigned short* __restrict__ startsT,    // ws: [2200][TROW] u16 (transposed)
        int P, int n) {
    __shared__ unsigned int histP[NPACK];        // run starts (packed u16)
    __shared__ unsigned int curP[NPACK];         // counts -> cursors
    __shared__ unsigned int stage[TILE];         // 48 KB sorted staging
    __shared__ unsigned int scr[34];

    int t = threadIdx.x;
    int blk = blockIdx.x;
    int start = blk * TILE;

    for (int i = t; i < NPACK; i += THREADS) curP[i] = 0u;
    __syncthreads();

    // Phase A: read 12 pairs/thread (int4 x3, coalesced), keep in registers
    int cells[12];
    unsigned int lows[12];
#pragma unroll
    for (int j = 0; j < 3; ++j) {
        int base = start + j * (THREADS * 4) + t * 4;
        int k0 = j * 4;
        if (base + 3 < P) {
            int4 s = *reinterpret_cast<const int4*>(src_idx + base);
            int4 d = *reinterpret_cast<const int4*>(dst_idx + base);
            int4 l = *reinterpret_cast<const int4*>(path_len + base);
            int lp = base - start;
            cells[k0]     = s.x * n + d.x;
            cells[k0 + 1] = s.y * n + d.y;
            cells[k0 + 2] = s.z * n + d.z;
            cells[k0 + 3] = s.w * n + d.w;
            lows[k0]     = ((unsigned int)(lp + 1) << 3) | (unsigned int)((l.x < 5 ? l.x : 5) - 1);
            lows[k0 + 1] = ((unsigned int)(lp + 2) << 3) | (unsigned int)((l.y < 5 ? l.y : 5) - 1);
            lows[k0 + 2] = ((unsigned int)(lp + 3) << 3) | (unsigned int)((l.z < 5 ? l.z : 5) - 1);
            lows[k0 + 3] = ((unsigned int)(lp + 4) << 3) | (unsigned int)((l.w < 5 ? l.w : 5) - 1);
        } else {
#pragma unroll
            for (int jj = 0; jj < 4; ++jj) {
                int p = base + jj;
                if (p < P) {
                    cells[k0 + jj] = src_idx[p] * n + dst_idx[p];
                    int len = path_len[p];
                    int cl = (len < 5 ? len : 5) - 1;
                    lows[k0 + jj] = ((unsigned int)(p - start + 1) << 3) | (unsigned int)cl;
                } else {
                    cells[k0 + jj] = -1;
                    lows[k0 + jj] = 0u;
                }
            }
        }
    }
#pragma unroll
    for (int k = 0; k < 12; ++k) {
        if (cells[k] >= 0) {
            unsigned int c = (unsigned int)cells[k] >> BSHIFT;
            atomicAdd(&curP[c >> 1], (c & 1) ? 0x10000u : 1u);
        }
    }
    __syncthreads();

    // Phase B: block-wide exclusive scan of counts -> run starts (histP).
    // Buckets 2198/2199 count 0 => histP entry 2198 == total (sentinel).
    unsigned int l0 = 0, l1 = 0, l2v = 0, l3 = 0, s = 0;
    if (t < NOWN) {
        unsigned int w0 = curP[2 * t], w1 = curP[2 * t + 1];
        unsigned int v0 = w0 & 0xFFFFu, v1 = w0 >> 16;
        unsigned int v2 = w1 & 0xFFFFu, v3 = w1 >> 16;
        l0 = 0; l1 = v0; l2v = v0 + v1; l3 = v0 + v1 + v2;
        s = v0 + v1 + v2 + v3;
    }
    unsigned int x = s;
    for (int d = 1; d < 64; d <<= 1) {
        unsigned int y = (unsigned int)__shfl_up((int)x, d, 64);
        if ((t & 63) >= d) x += y;
    }
    if ((t & 63) == 63) scr[t >> 6] = x;
    __syncthreads();
    if (t == 0) {
        unsigned int acc = 0;
        for (int w = 0; w < 16; ++w) { unsigned int v = scr[w]; scr[16 + w] = acc; acc += v; }
        scr[32] = acc;
    }
    __syncthreads();
    unsigned int exc = x - s + scr[16 + (t >> 6)];
    if (t < NOWN) {
        unsigned int st0 = exc + l0, st1 = exc + l1, st2 = exc + l2v, st3 = exc + l3;
        histP[2 * t]     = (st0 & 0xFFFFu) | (st1 << 16);
        histP[2 * t + 1] = (st2 & 0xFFFFu) | (st3 << 16);
    }
    __syncthreads();

    // Phase C: cursors := starts
    for (int i = t; i < NPACK; i += THREADS) curP[i] = histP[i];
    __syncthreads();

    // Phase D: place records into LDS staging, grouped by bucket
#pragma unroll
    for (int k = 0; k < 12; ++k) {
        if (cells[k] >= 0) {
            unsigned int cell = (unsigned int)cells[k];
            unsigned int c = cell >> BSHIFT;
            unsigned int old = atomicAdd(&curP[c >> 1], (c & 1) ? 0x10000u : 1u);
            unsigned int pos = (old >> ((c & 1) * 16)) & 0xFFFFu;
            stage[pos] = ((cell & (BCELLS - 1)) << 18) | lows[k];
        }
    }
    __syncthreads();

    // Phase E: contiguous vectorized dump of sorted records + TRANSPOSED starts
    unsigned int tot = scr[32];
    uint4* dst4 = reinterpret_cast<uint4*>(recsW + (size_t)blk * TILE);
    const uint4* st4 = reinterpret_cast<const uint4*>(stage);
    unsigned int n4 = (tot + 3) >> 2;
    for (unsigned int i = t; i < n4; i += THREADS) dst4[i] = st4[i];
    // startsT[c][blk] for c = 0..2198 (row 2198 = per-region total, the sentinel).
    // Scattered u16 stores; footprint only 2.9 MB -> L2 write-combined.
    for (int c = t; c <= NBUCK; c += THREADS)
        startsT[(size_t)c * TROW + blk] = (unsigned short)unpack16(histP, (unsigned int)c);
}

// ---------------- K2: grouped per-bucket gather-merge + decode ----------------
__device__ __forceinline__ float se_decode(unsigned int k,
                                           float b0, float b1, float b2,
                                           float b3, float b4) {
    unsigned c = k & 7u;
    float t = (c == 0u) ? b0 : (c == 1u) ? b1 : (c == 2u) ? b2 : (c == 3u) ? b3 : b4;
    return k ? t : 0.0f;
}

__global__ __launch_bounds__(THREADS) void se_merge(
        const unsigned int* __restrict__ recsW,
        const unsigned short* __restrict__ startsT,
        const float* __restrict__ b,
        float* __restrict__ out,
        long long totalCells, int nblk) {
    __shared__ unsigned int tab[BCELLS];      // 64 KB

    int g = blockIdx.x;
    int tr = threadIdx.x;
    float b0 = b[0], b1 = b[1], b2 = b[2], b3 = b[3], b4 = b[4];

#pragma unroll
    for (int k = 0; k < MGROUP; ++k) {
        int c = g * MGROUP + k;                   // bucket index, <= 2197
        // zero the tab
        uint4* tab4 = reinterpret_cast<uint4*>(tab);
        for (int i = tr; i < BCELLS / 4; i += THREADS)
            tab4[i] = make_uint4(0u, 0u, 0u, 0u);
        __syncthreads();

        // gather: one thread per region; span = [startsT[c][r], startsT[c+1][r])
        // within region r's sorted records. Spans for k=0,1 are ADJACENT.
        if (tr < nblk) {
            unsigned int rb0 = startsT[(size_t)c * TROW + tr];
            unsigned int rb1 = startsT[(size_t)(c + 1) * TROW + tr];
            const unsigned int* rr = recsW + (size_t)tr * TILE;
            unsigned int keyhi = (unsigned int)(tr + 1) << 18;
            for (unsigned int i = rb0; i < rb1; ++i) {
                unsigned int rec = rr[i];
                atomicMax(&tab[rec >> 18], keyhi | (rec & 0x3FFFFu));
            }
        }
        __syncthreads();

        // decode + coalesced store of this bucket's cells
        long long baseCell = (long long)c << BSHIFT;
        long long rem = totalCells - baseCell;
        int valid = rem < BCELLS ? (int)rem : BCELLS;
        float* o = out + baseCell;
        int nq = valid >> 2;
        float4* o4 = reinterpret_cast<float4*>(o);
        for (int i = tr; i < nq; i += THREADS) {
            uint4 kk = tab4[i];
            float4 v;
            v.x = se_decode(kk.x, b0, b1, b2, b3, b4);
            v.y = se_decode(kk.y, b0, b1, b2, b3, b4);
            v.z = se_decode(kk.z, b0, b1, b2, b3, b4);
            v.w = se_decode(kk.w, b0, b1, b2, b3, b4);
            o4[i] = v;
        }
        for (int i = (nq << 2) + tr; i < valid; i += THREADS)
            o[i] = se_decode(tab[i], b0, b1, b2, b3, b4);
        __syncthreads();   // protect tab reads before next pass's zero
    }
}

extern "C" void kernel_launch(void* const* d_in, const int* in_sizes, int n_in,
                              void* d_out, int out_size, void* d_ws, size_t ws_size,
                              hipStream_t stream) {
    // inputs: 0=x [N*128 f32], 1=b [5 f32], 2=src_idx [P i32], 3=dst_idx [P i32], 4=path_len [P i32]
    const float* b        = (const float*)d_in[1];
    const int*   src_idx  = (const int*)d_in[2];
    const int*   dst_idx  = (const int*)d_in[3];
    const int*   path_len = (const int*)d_in[4];
    int P = in_sizes[2];
    int n = in_sizes[0] / 128;                      // N = 6000
    long long totalCells = (long long)n * n;        // 36,000,000
    int nblk = (P + TILE - 1) / TILE;               // 652

    // ws layout: recsW [nblk*TILE u32] (32MB) then startsT [2200*TROW u16]
    // (2.89MB). recsW read-range and all used startsT rows fully overwritten
    // every call — no memset needed.
    unsigned int*   recsW   = (unsigned int*)d_ws;
    unsigned short* startsT = (unsigned short*)(recsW + (size_t)nblk * TILE);

    // K1: per-tile LDS bucket-sort -> block-local sorted recs + transposed starts
    se_sort<<<nblk, THREADS, 0, stream>>>(src_idx, dst_idx, path_len,
                                          recsW, startsT, P, n);

    // K2: grouped gather-merge (2 buckets/block, sequential tab passes) + decode
    se_merge<<<NBUCK / MGROUP, THREADS, 0, stream>>>(recsW, startsT, b,
                                                     (float*)d_out, totalCells, nblk);
}